// Round 1
// baseline (441.657 us; speedup 1.0000x reference)
//
#include <hip/hip_runtime.h>
#include <hip/hip_bf16.h>

#define NN 384          // nodes
#define CC 128
#define HH 60
#define NEL (CC*HH)     // 7680 per node
#define NLAYERS 4

// ---------------- sort edges by dst (counting sort), single block ----------------
__global__ void k_sort(const int* __restrict__ ei, int E,
                       int* __restrict__ off, int* __restrict__ ssrc, int* __restrict__ seid) {
    __shared__ int cnt[NN + 1];
    __shared__ int cur[NN];
    int t = threadIdx.x;
    for (int i = t; i < NN + 1; i += 256) cnt[i] = 0;
    __syncthreads();
    const int* src = ei;
    const int* dst = ei + E;
    for (int e = t; e < E; e += 256) atomicAdd(&cnt[dst[e] + 1], 1);
    __syncthreads();
    if (t == 0) {
        int s = 0;
        for (int i = 0; i <= NN; i++) { s += cnt[i]; cnt[i] = s; }
    }
    __syncthreads();
    for (int i = t; i < NN + 1; i += 256) off[i] = cnt[i];
    for (int i = t; i < NN; i += 256) cur[i] = cnt[i];
    __syncthreads();
    for (int e = t; e < E; e += 256) {
        int d = dst[e];
        int p = atomicAdd(&cur[d], 1);
        ssrc[p] = src[e];
        seid[p] = e;
    }
}

// ---------------- fold edge linear through W3: M3 = W3@ew (C,5), v3 = W3@eb (C) ----------------
// grid: 4 blocks (layers), 128 threads (c)
__global__ void k_prep(const float* __restrict__ cw, const float* __restrict__ ew,
                       const float* __restrict__ eb, float* __restrict__ M3, float* __restrict__ v3) {
    int l = blockIdx.x, c = threadIdx.x;
    const float* wrow = cw + (l * CC + c) * (3 * CC) + 2 * CC; // W3 row c
    const float* ewl = ew + l * CC * 5;
    const float* ebl = eb + l * CC;
    float m0 = 0, m1 = 0, m2 = 0, m3 = 0, m4 = 0, v = 0;
    for (int k = 0; k < CC; k++) {
        float w = wrow[k];
        const float* e5 = ewl + k * 5;
        m0 = fmaf(w, e5[0], m0); m1 = fmaf(w, e5[1], m1); m2 = fmaf(w, e5[2], m2);
        m3 = fmaf(w, e5[3], m3); m4 = fmaf(w, e5[4], m4);
        v  = fmaf(w, ebl[k], v);
    }
    float* mo = M3 + (l * CC + c) * 5;
    mo[0] = m0; mo[1] = m1; mo[2] = m2; mo[3] = m3; mo[4] = m4;
    v3[l * CC + c] = v;
}

// ---------------- pre-transpose combined W: wt[l][k][r], r<128: W1-W2 row r col k; r>=128: W2 ----------------
// grid: 4*128 blocks (l,k), 256 threads (r)
__global__ void k_wprep(const float* __restrict__ cw, float* __restrict__ wt) {
    int l = blockIdx.x >> 7, k = blockIdx.x & 127, r = threadIdx.x;
    const float* cwl = cw + l * CC * 3 * CC;
    float v;
    if (r < 128) v = cwl[r * 384 + k] - cwl[r * 384 + 128 + k];
    else         v = cwl[(r - 128) * 384 + 128 + k];
    wt[(l * 128 + k) * 256 + r] = v;
}

// ---------------- per-node matmul: A[n]=(W1-W2)@x_n, B[n]=W2@x_n ----------------
// grid: 384 blocks (node), 256 threads; 8x8 register tile over 256 rows x 64 cols (60 valid)
__global__ __launch_bounds__(256) void k_node_mm(const float* __restrict__ x,
                                                 const float* __restrict__ wt,
                                                 float* __restrict__ A, float* __restrict__ B) {
    __shared__ __align__(16) float Xs[NEL + 8];
    __shared__ __align__(16) float Ws[32 * 256];
    int n = blockIdx.x, t = threadIdx.x;
    const float* xn = x + n * NEL;
#pragma unroll
    for (int i = 0; i < 30; i++) Xs[t + 256 * i] = xn[t + 256 * i];

    float acc[8][8];
#pragma unroll
    for (int i = 0; i < 8; i++)
#pragma unroll
        for (int j = 0; j < 8; j++) acc[i][j] = 0.f;

    int r0 = (t >> 3) << 3;
    int h0 = (t & 7) << 3;

    for (int kc = 0; kc < 128; kc += 32) {
        __syncthreads();
        const float4* wsrc = (const float4*)(wt + kc * 256);
        float4* wdst = (float4*)Ws;
#pragma unroll
        for (int i = 0; i < 8; i++) wdst[t + 256 * i] = wsrc[t + 256 * i];
        __syncthreads();
#pragma unroll
        for (int kk = 0; kk < 32; kk++) {
            int k = kc + kk;
            float4 xv0 = *(const float4*)&Xs[k * HH + h0];
            float4 xv1 = *(const float4*)&Xs[k * HH + h0 + 4];
            float4 wv0 = *(const float4*)&Ws[kk * 256 + r0];
            float4 wv1 = *(const float4*)&Ws[kk * 256 + r0 + 4];
            float wv[8] = {wv0.x, wv0.y, wv0.z, wv0.w, wv1.x, wv1.y, wv1.z, wv1.w};
            float xv[8] = {xv0.x, xv0.y, xv0.z, xv0.w, xv1.x, xv1.y, xv1.z, xv1.w};
#pragma unroll
            for (int i = 0; i < 8; i++)
#pragma unroll
                for (int j = 0; j < 8; j++) acc[i][j] = fmaf(wv[i], xv[j], acc[i][j]);
        }
    }
    // store valid columns
    float* outp = (r0 < 128) ? (A + n * NEL + r0 * HH + h0)
                             : (B + n * NEL + (r0 - 128) * HH + h0);
    int hmax = 60 - h0; if (hmax > 8) hmax = 8;
#pragma unroll
    for (int i = 0; i < 8; i++)
        for (int j = 0; j < hmax; j++) outp[i * HH + j] = acc[i][j];
}

// ---------------- per-dst aggregation: t = A[d]+B[s]+c3, LN over (C,H), relu, sum ----------------
// grid: 384 blocks (dst), 256 threads
__global__ __launch_bounds__(256) void k_edge(
    const float* __restrict__ A, const float* __restrict__ B,
    const float* __restrict__ ea, const float* __restrict__ M3, const float* __restrict__ v3,
    const float* __restrict__ g, const float* __restrict__ b,
    const int* __restrict__ off, const int* __restrict__ ssrc, const int* __restrict__ seid,
    float* __restrict__ out) {
    int d = blockIdx.x, t = threadIdx.x;
    __shared__ float M3s[CC * 5];
    __shared__ float v3s[CC];
    __shared__ float c3s[CC];
    __shared__ float red[8];

    for (int i = t; i < CC * 5; i += 256) M3s[i] = M3[i];
    if (t < CC) v3s[t] = v3[t];

    float areg[30], greg[30], breg[30], accv[30];
    int cidx[30];
#pragma unroll
    for (int i = 0; i < 30; i++) {
        int p = t + (i << 8);
        areg[i] = A[d * NEL + p];
        greg[i] = g[p];
        breg[i] = b[p];
        accv[i] = 0.f;
        cidx[i] = p / HH;
    }
    __syncthreads();

    int j0 = off[d], j1 = off[d + 1];
    for (int j = j0; j < j1; j++) {
        int s = ssrc[j], eid = seid[j];
        if (t < CC) {
            const float* eap = ea + eid * 5;
            float e0 = eap[0], e1 = eap[1], e2 = eap[2], e3 = eap[3], e4 = eap[4];
            const float* m = &M3s[t * 5];
            c3s[t] = v3s[t] + m[0]*e0 + m[1]*e1 + m[2]*e2 + m[3]*e3 + m[4]*e4;
        }
        __syncthreads();
        const float* Bs = B + s * NEL;
        float tv[30];
        float sum = 0.f, sq = 0.f;
#pragma unroll
        for (int i = 0; i < 30; i++) {
            float v = areg[i] + Bs[t + (i << 8)] + c3s[cidx[i]];
            tv[i] = v;
            sum += v;
            sq = fmaf(v, v, sq);
        }
#pragma unroll
        for (int o = 32; o; o >>= 1) { sum += __shfl_xor(sum, o); sq += __shfl_xor(sq, o); }
        if ((t & 63) == 0) { red[(t >> 6) * 2] = sum; red[(t >> 6) * 2 + 1] = sq; }
        __syncthreads();
        float fs = red[0] + red[2] + red[4] + red[6];
        float fq = red[1] + red[3] + red[5] + red[7];
        float mu = fs * (1.0f / NEL);
        float var = fq * (1.0f / NEL) - mu * mu;
        float rs = rsqrtf(var + 1e-5f);
#pragma unroll
        for (int i = 0; i < 30; i++) {
            float v = (tv[i] - mu) * rs * greg[i] + breg[i];
            accv[i] += fmaxf(v, 0.f);
        }
    }
#pragma unroll
    for (int i = 0; i < 30; i++) out[d * NEL + t + (i << 8)] = accv[i];
}

extern "C" void kernel_launch(void* const* d_in, const int* in_sizes, int n_in,
                              void* d_out, int out_size, void* d_ws, size_t ws_size,
                              hipStream_t stream) {
    const float* x  = (const float*)d_in[0];
    const float* ea = (const float*)d_in[1];
    const float* ew = (const float*)d_in[2];
    const float* eb = (const float*)d_in[3];
    const float* cw = (const float*)d_in[4];
    const float* lg = (const float*)d_in[5];
    const float* lb = (const float*)d_in[6];
    const int*   ei = (const int*)d_in[7];
    int E = in_sizes[7] / 2;
    float* out = (float*)d_out;

    // workspace carve-up (floats)
    float* wsf  = (float*)d_ws;
    float* Abuf = wsf;                       // 384*7680
    float* Bbuf = Abuf + NN * NEL;           // 384*7680
    float* xbuf = Bbuf + NN * NEL;           // 384*7680
    float* wt   = xbuf + NN * NEL;           // 4*128*256
    float* M3   = wt + 4 * 128 * 256;        // 4*128*5
    float* v3   = M3 + 4 * CC * 5;           // 4*128
    int* off  = (int*)(v3 + 4 * CC);         // 385
    int* ssrc = off + (NN + 1);              // E
    int* seid = ssrc + E;                    // E

    k_sort<<<1, 256, 0, stream>>>(ei, E, off, ssrc, seid);
    k_prep<<<4, 128, 0, stream>>>(cw, ew, eb, M3, v3);
    k_wprep<<<4 * 128, 256, 0, stream>>>(cw, wt);

    for (int l = 0; l < NLAYERS; l++) {
        const float* xin = (l == 0) ? x : xbuf;
        float* xout = (l == NLAYERS - 1) ? out : xbuf;
        k_node_mm<<<NN, 256, 0, stream>>>(xin, wt + l * 128 * 256, Abuf, Bbuf);
        k_edge<<<NN, 256, 0, stream>>>(Abuf, Bbuf, ea, M3 + l * CC * 5, v3 + l * CC,
                                       lg + l * NEL, lb + l * NEL,
                                       off, ssrc, seid, xout);
    }
}

// Round 3
// 275.494 us; speedup vs baseline: 1.6031x; 1.6031x over previous
//
#include <hip/hip_runtime.h>
#include <hip/hip_bf16.h>

#define NN 384          // nodes
#define CC 128
#define HH 60
#define NEL (CC*HH)     // 7680 per node
#define NLAYERS 4

// ---------------- sort edges by dst (counting sort), single block ----------------
__global__ void k_sort(const int* __restrict__ ei, int E,
                       int* __restrict__ off, int* __restrict__ ssrc, int* __restrict__ seid) {
    __shared__ int cnt[NN + 1];
    __shared__ int cur[NN];
    int t = threadIdx.x;
    for (int i = t; i < NN + 1; i += 256) cnt[i] = 0;
    __syncthreads();
    const int* src = ei;
    const int* dst = ei + E;
    for (int e = t; e < E; e += 256) atomicAdd(&cnt[dst[e] + 1], 1);
    __syncthreads();
    if (t == 0) {
        int s = 0;
        for (int i = 0; i <= NN; i++) { s += cnt[i]; cnt[i] = s; }
    }
    __syncthreads();
    for (int i = t; i < NN + 1; i += 256) off[i] = cnt[i];
    for (int i = t; i < NN; i += 256) cur[i] = cnt[i];
    __syncthreads();
    for (int e = t; e < E; e += 256) {
        int d = dst[e];
        int p = atomicAdd(&cur[d], 1);
        ssrc[p] = src[e];
        seid[p] = e;
    }
}

// ---------------- fold edge linear through W3: M3 = W3@ew (C,5), v3 = W3@eb (C) ----------------
__global__ void k_prep(const float* __restrict__ cw, const float* __restrict__ ew,
                       const float* __restrict__ eb, float* __restrict__ M3, float* __restrict__ v3) {
    int l = blockIdx.x, c = threadIdx.x;
    const float* wrow = cw + (l * CC + c) * (3 * CC) + 2 * CC; // W3 row c
    const float* ewl = ew + l * CC * 5;
    const float* ebl = eb + l * CC;
    float m0 = 0, m1 = 0, m2 = 0, m3 = 0, m4 = 0, v = 0;
    for (int k = 0; k < CC; k++) {
        float w = wrow[k];
        const float* e5 = ewl + k * 5;
        m0 = fmaf(w, e5[0], m0); m1 = fmaf(w, e5[1], m1); m2 = fmaf(w, e5[2], m2);
        m3 = fmaf(w, e5[3], m3); m4 = fmaf(w, e5[4], m4);
        v  = fmaf(w, ebl[k], v);
    }
    float* mo = M3 + (l * CC + c) * 5;
    mo[0] = m0; mo[1] = m1; mo[2] = m2; mo[3] = m3; mo[4] = m4;
    v3[l * CC + c] = v;
}

// ---------------- pre-transpose combined W: wt[l][k][r], r<128: W1-W2 row r col k; r>=128: W2 ----------------
__global__ void k_wprep(const float* __restrict__ cw, float* __restrict__ wt) {
    int l = blockIdx.x >> 7, k = blockIdx.x & 127, r = threadIdx.x;
    const float* cwl = cw + l * CC * 3 * CC;
    float v;
    if (r < 128) v = cwl[r * 384 + k] - cwl[r * 384 + 128 + k];
    else         v = cwl[(r - 128) * 384 + 128 + k];
    wt[(l * 128 + k) * 256 + r] = v;
}

// ---------------- per-node matmul: A[n]=(W1-W2)@x_n, B[n]=W2@x_n ----------------
// grid: 768 blocks = (node, half-rows). Block: 256 threads, 128 rows x 60 cols, K=128.
// LDS: X 32KB (stride-64) + W chunk 16KB (32 k). Thread tile 4 rows x 8 cols.
__global__ __launch_bounds__(256) void k_node_mm(const float* __restrict__ x,
                                                 const float* __restrict__ wt,
                                                 float* __restrict__ A, float* __restrict__ B) {
    __shared__ __align__(16) float Xs[128 * 64];    // [k][h] stride 64
    __shared__ __align__(16) float Ws[32 * 128];    // [kk][r] chunk
    int n = blockIdx.x >> 1, half = blockIdx.x & 1;
    int t = threadIdx.x;

    // stage X: 1920 float4 (60 floats = 15 f4 per k-row -> stride-64 dest)
    const float4* x4 = (const float4*)(x + n * NEL);
    for (int idx = t; idx < 1920; idx += 256) {
        int k = idx / 15;
        int h4 = idx - k * 15;
        *(float4*)&Xs[(k << 6) + (h4 << 2)] = x4[idx];
    }
    // zero pad cols 60..63
    for (int idx = t; idx < 512; idx += 256) Xs[((idx >> 2) << 6) + 60 + (idx & 3)] = 0.f;

    int trow = t >> 3, tcol = t & 7;
    int r0 = trow << 2, h0 = tcol << 3;
    float acc[4][8];
#pragma unroll
    for (int i = 0; i < 4; i++)
#pragma unroll
        for (int j = 0; j < 8; j++) acc[i][j] = 0.f;

    const float4* w4 = (const float4*)wt;   // layer base, rows as 64 f4 per k
    float4* Ws4 = (float4*)Ws;

    for (int c = 0; c < 4; c++) {
        __syncthreads();
        // stage 32 k-rows x 128 floats = 1024 f4
#pragma unroll
        for (int i = 0; i < 4; i++) {
            int g = t + (i << 8);
            Ws4[g] = w4[(((c << 5) + (g >> 5)) << 6) + (half << 5) + (g & 31)];
        }
        __syncthreads();
#pragma unroll 4
        for (int kk = 0; kk < 32; kk++) {
            float4 wv = *(const float4*)&Ws[(kk << 7) + r0];
            const float* xp = &Xs[(((c << 5) + kk) << 6)];
            float4 xa = *(const float4*)&xp[h0];
            float4 xb = *(const float4*)&xp[h0 + 4];
            float xv[8] = {xa.x, xa.y, xa.z, xa.w, xb.x, xb.y, xb.z, xb.w};
            float wr[4] = {wv.x, wv.y, wv.z, wv.w};
#pragma unroll
            for (int i = 0; i < 4; i++)
#pragma unroll
                for (int j = 0; j < 8; j++) acc[i][j] = fmaf(wr[i], xv[j], acc[i][j]);
        }
    }

    float* base = (half ? B : A) + n * NEL;
#pragma unroll
    for (int i = 0; i < 4; i++) {
        float* dst = base + (r0 + i) * 60 + h0;
        *(float4*)dst = make_float4(acc[i][0], acc[i][1], acc[i][2], acc[i][3]);
        if (h0 < 56)
            *(float4*)(dst + 4) = make_float4(acc[i][4], acc[i][5], acc[i][6], acc[i][7]);
    }
}

// ---------------- per-dst aggregation: t = A[d]+B[s]+c3, LN over (C,H), relu, sum ----------------
// grid: 384 blocks (dst), 256 threads, float2-vectorized. 1 barrier per edge.
__global__ __launch_bounds__(256) void k_edge(
    const float* __restrict__ A, const float* __restrict__ Bm,
    const float* __restrict__ ea, const float* __restrict__ M3, const float* __restrict__ v3,
    const float* __restrict__ g, const float* __restrict__ b,
    const int* __restrict__ off, const int* __restrict__ ssrc, const int* __restrict__ seid,
    float* __restrict__ out) {
    int d = blockIdx.x, t = threadIdx.x;
    __shared__ float c3all[16 * 128];
    __shared__ float red[2][8];

    int j0 = off[d], j1 = off[d + 1], cnt = j1 - j0;   // == 8 for this graph

    // upfront c3 for all edges of this dst
    for (int idx = t; idx < (cnt << 7); idx += 256) {
        int j = idx >> 7, c = idx & 127;
        int eid = seid[j0 + j];
        const float* eap = ea + eid * 5;
        const float* m = M3 + c * 5;
        c3all[idx] = v3[c] + m[0]*eap[0] + m[1]*eap[1] + m[2]*eap[2] + m[3]*eap[3] + m[4]*eap[4];
    }

    float2 areg[15], greg[15], breg[15], accv[15];
    int cidx[15];
    const float2* A2 = (const float2*)(A + d * NEL);
    const float2* g2 = (const float2*)g;
    const float2* b2 = (const float2*)b;
#pragma unroll
    for (int i = 0; i < 15; i++) {
        int p = t + (i << 8);
        areg[i] = A2[p]; greg[i] = g2[p]; breg[i] = b2[p];
        accv[i] = make_float2(0.f, 0.f);
        cidx[i] = (p << 1) / 60;      // both elems of a float2 share one channel
    }
    __syncthreads();

    for (int j = 0; j < cnt; j++) {
        int s = ssrc[j0 + j];
        const float2* B2 = (const float2*)(Bm + s * NEL);
        const float* c3 = &c3all[j << 7];
        float2 tv[15];
        float sum = 0.f, sq = 0.f;
#pragma unroll
        for (int i = 0; i < 15; i++) {
            float2 bv = B2[t + (i << 8)];
            float cc = c3[cidx[i]];
            float vx = areg[i].x + bv.x + cc;
            float vy = areg[i].y + bv.y + cc;
            tv[i] = make_float2(vx, vy);
            sum += vx + vy;
            sq = fmaf(vx, vx, fmaf(vy, vy, sq));
        }
#pragma unroll
        for (int o = 32; o; o >>= 1) { sum += __shfl_xor(sum, o); sq += __shfl_xor(sq, o); }
        int jb = j & 1;
        if ((t & 63) == 0) { red[jb][(t >> 6) * 2] = sum; red[jb][(t >> 6) * 2 + 1] = sq; }
        __syncthreads();
        float fs = red[jb][0] + red[jb][2] + red[jb][4] + red[jb][6];
        float fq = red[jb][1] + red[jb][3] + red[jb][5] + red[jb][7];
        float mu = fs * (1.0f / NEL);
        float var = fq * (1.0f / NEL) - mu * mu;
        float rs = rsqrtf(var + 1e-5f);
#pragma unroll
        for (int i = 0; i < 15; i++) {
            float nx = (tv[i].x - mu) * rs * greg[i].x + breg[i].x;
            float ny = (tv[i].y - mu) * rs * greg[i].y + breg[i].y;
            accv[i].x += fmaxf(nx, 0.f);
            accv[i].y += fmaxf(ny, 0.f);
        }
    }
    float2* out2 = (float2*)(out + d * NEL);
#pragma unroll
    for (int i = 0; i < 15; i++) out2[t + (i << 8)] = accv[i];
}

extern "C" void kernel_launch(void* const* d_in, const int* in_sizes, int n_in,
                              void* d_out, int out_size, void* d_ws, size_t ws_size,
                              hipStream_t stream) {
    const float* x  = (const float*)d_in[0];
    const float* ea = (const float*)d_in[1];
    const float* ew = (const float*)d_in[2];
    const float* eb = (const float*)d_in[3];
    const float* cw = (const float*)d_in[4];
    const float* lg = (const float*)d_in[5];
    const float* lb = (const float*)d_in[6];
    const int*   ei = (const int*)d_in[7];
    int E = in_sizes[7] / 2;
    float* out = (float*)d_out;

    float* wsf  = (float*)d_ws;
    float* Abuf = wsf;                       // 384*7680
    float* Bbuf = Abuf + NN * NEL;           // 384*7680
    float* xbuf = Bbuf + NN * NEL;           // 384*7680
    float* wt   = xbuf + NN * NEL;           // 4*128*256
    float* M3   = wt + 4 * 128 * 256;        // 4*128*5
    float* v3   = M3 + 4 * CC * 5;           // 4*128
    int* off  = (int*)(v3 + 4 * CC);         // 385
    int* ssrc = off + (NN + 1);              // E
    int* seid = ssrc + E;                    // E

    k_sort<<<1, 256, 0, stream>>>(ei, E, off, ssrc, seid);
    k_prep<<<4, 128, 0, stream>>>(cw, ew, eb, M3, v3);
    k_wprep<<<4 * 128, 256, 0, stream>>>(cw, wt);

    for (int l = 0; l < NLAYERS; l++) {
        const float* xin = (l == 0) ? x : xbuf;
        float* xout = (l == NLAYERS - 1) ? out : xbuf;
        k_node_mm<<<2 * NN, 256, 0, stream>>>(xin, wt + l * 128 * 256, Abuf, Bbuf);
        k_edge<<<NN, 256, 0, stream>>>(Abuf, Bbuf, ea, M3 + l * CC * 5, v3 + l * CC,
                                       lg + l * NEL, lb + l * NEL,
                                       off, ssrc, seid, xout);
    }
}

// Round 5
// 268.817 us; speedup vs baseline: 1.6430x; 1.0248x over previous
//
#include <hip/hip_runtime.h>
#include <hip/hip_bf16.h>

#define NN 384
#define CC 128
#define HH 60
#define NEL (CC*HH)       // 7680
#define NELP (64*128)     // 8192 padded hc
#define NLAYERS 4

typedef _Float16 f16x4 __attribute__((ext_vector_type(4)));
typedef float f32x4 __attribute__((ext_vector_type(4)));

__device__ __forceinline__ void cvt2(float v, _Float16& hi, _Float16& lo) {
    hi = (_Float16)v;
    lo = (_Float16)(v - (float)hi);
}

// ---------------- sort edges by dst (counting sort), single block ----------------
__global__ void k_sort(const int* __restrict__ ei, int E,
                       int* __restrict__ off, int* __restrict__ ssrc, int* __restrict__ seid) {
    __shared__ int cnt[NN + 1];
    __shared__ int cur[NN];
    int t = threadIdx.x;
    for (int i = t; i < NN + 1; i += 256) cnt[i] = 0;
    __syncthreads();
    const int* src = ei;
    const int* dst = ei + E;
    for (int e = t; e < E; e += 256) atomicAdd(&cnt[dst[e] + 1], 1);
    __syncthreads();
    if (t == 0) {
        int s = 0;
        for (int i = 0; i <= NN; i++) { s += cnt[i]; cnt[i] = s; }
    }
    __syncthreads();
    for (int i = t; i < NN + 1; i += 256) off[i] = cnt[i];
    for (int i = t; i < NN; i += 256) cur[i] = cnt[i];
    __syncthreads();
    for (int e = t; e < E; e += 256) {
        int d = dst[e];
        int p = atomicAdd(&cur[d], 1);
        ssrc[p] = src[e];
        seid[p] = e;
    }
}

// ---------------- fold edge linear through W3: M3 = W3@ew (C,5), v3 = W3@eb (C) ----------------
__global__ void k_prep(const float* __restrict__ cw, const float* __restrict__ ew,
                       const float* __restrict__ eb, float* __restrict__ M3, float* __restrict__ v3) {
    int l = blockIdx.x, c = threadIdx.x;
    const float* wrow = cw + (l * CC + c) * (3 * CC) + 2 * CC;
    const float* ewl = ew + l * CC * 5;
    const float* ebl = eb + l * CC;
    float m0 = 0, m1 = 0, m2 = 0, m3 = 0, m4 = 0, v = 0;
    for (int k = 0; k < CC; k++) {
        float w = wrow[k];
        const float* e5 = ewl + k * 5;
        m0 = fmaf(w, e5[0], m0); m1 = fmaf(w, e5[1], m1); m2 = fmaf(w, e5[2], m2);
        m3 = fmaf(w, e5[3], m3); m4 = fmaf(w, e5[4], m4);
        v  = fmaf(w, ebl[k], v);
    }
    float* mo = M3 + (l * CC + c) * 5;
    mo[0] = m0; mo[1] = m1; mo[2] = m2; mo[3] = m3; mo[4] = m4;
    v3[l * CC + c] = v;
}

// ---------------- W -> f16 hi/lo MFMA fragments ----------------
// combined rows r: r<128 -> W1-W2 ; r>=128 -> W2. frag: lane l holds k=(kt*16+(l>>4)*4+j), col r=ng*16+(l&15)
// layout: wf[((l*16+ng)*8+kt)*256 + lane*4 + j]
__global__ void k_wfrag(const float* __restrict__ cw, _Float16* __restrict__ wfh, _Float16* __restrict__ wfl) {
    int bb = blockIdx.x, l = bb >> 4, ng = bb & 15, lane = threadIdx.x;
    const float* cwl = cw + l * CC * 3 * CC;
    int r = (ng << 4) + (lane & 15);
#pragma unroll
    for (int kt = 0; kt < 8; kt++) {
#pragma unroll
        for (int j = 0; j < 4; j++) {
            int k = (kt << 4) + ((lane >> 4) << 2) + j;
            float wv;
            if (r < 128) wv = cwl[r * 384 + k] - cwl[r * 384 + 128 + k];
            else         wv = cwl[(r - 128) * 384 + 128 + k];
            _Float16 hi, lo; cvt2(wv, hi, lo);
            int idx = ((bb) * 8 + kt) * 256 + lane * 4 + j;
            wfh[idx] = hi; wfl[idx] = lo;
        }
    }
}

// ---------------- permute ln_g / ln_b to hc layout ----------------
__global__ void k_gbprep(const float* __restrict__ g, const float* __restrict__ b,
                         float* __restrict__ gp, float* __restrict__ bp) {
    int idx = blockIdx.x * 256 + threadIdx.x;     // 0..30719
    int l = idx / NEL, q = idx - l * NEL;
    int c = q & 127, h = q >> 7;
    gp[idx] = g[l * NEL + c * HH + h];
    bp[idx] = b[l * NEL + c * HH + h];
}

// ---------------- node GEMM via MFMA f16x3 split ----------------
// grid 384 (node), 512 threads (8 waves). Wave w covers output cols r in [w*32, w*32+32).
// D[h=0..63][r=0..255]; A-operand = X (hc layout, LDS swizzled), B-operand = W frags (registers).
template<int L0>
__global__ __launch_bounds__(512) void k_mm(const float* __restrict__ xin,
                                            const _Float16* __restrict__ wfh,
                                            const _Float16* __restrict__ wfl,
                                            float* __restrict__ Ab, float* __restrict__ Bb) {
    __shared__ __align__(16) _Float16 Xh[64 * 128];
    __shared__ __align__(16) _Float16 Xl[64 * 128];
    int n = blockIdx.x, t = threadIdx.x;
    int w = t >> 6, lane = t & 63;

    // W fragments in registers (per wave: ng = w*2+nt)
    f16x4 wh[2][8], wl[2][8];
#pragma unroll
    for (int nt = 0; nt < 2; nt++)
#pragma unroll
        for (int kt = 0; kt < 8; kt++) {
            int idx = ((w * 2 + nt) * 8 + kt) * 256 + lane * 4;
            wh[nt][kt] = *(const f16x4*)(wfh + idx);
            wl[nt][kt] = *(const f16x4*)(wfl + idx);
        }

    // stage X -> LDS hi/lo f16 planes, row h (256B) with XOR swizzle on bits 4..6
    if (L0) {
        const float* xn = xin + n * NEL;    // canonical [c][h]
#pragma unroll
        for (int i = 0; i < 8; i++) {
            int p = t + (i << 9);
            if (p < 3840) {
                int q = p << 1;
                int c = q & 127, h = q >> 7;
                float v0 = xn[c * HH + h], v1 = xn[(c + 1) * HH + h];
                _Float16 h0, l0, h1, l1; cvt2(v0, h0, l0); cvt2(v1, h1, l1);
                int o = (h << 8) + (((c << 1)) ^ ((h & 7) << 4));
                union { _Float16 f[2]; uint u; } ph, pl;
                ph.f[0] = h0; ph.f[1] = h1; pl.f[0] = l0; pl.f[1] = l1;
                *(uint*)((char*)Xh + o) = ph.u;
                *(uint*)((char*)Xl + o) = pl.u;
            }
        }
        // zero pad rows 60..63 (512 elems per plane)
        {
            int h = 60 + (t >> 7), oc = (t & 127) << 1;
            int o = (h << 8) + (oc ^ ((h & 7) << 4));
            *(ushort*)((char*)Xh + o) = 0;
            *(ushort*)((char*)Xl + o) = 0;
        }
    } else {
        const float4* x4 = (const float4*)(xin + n * NELP);   // hc padded [64][128]
#pragma unroll
        for (int i = 0; i < 4; i++) {
            int idx = t + (i << 9);        // 0..2047 f4
            float4 v = x4[idx];
            int h = idx >> 5, c0 = (idx & 31) << 2;
            _Float16 hh0, ll0, hh1, ll1, hh2, ll2, hh3, ll3;
            cvt2(v.x, hh0, ll0); cvt2(v.y, hh1, ll1); cvt2(v.z, hh2, ll2); cvt2(v.w, hh3, ll3);
            int o = (h << 8) + (((c0 << 1)) ^ ((h & 7) << 4));
            union { _Float16 f[4]; uint2 u; } ph, pl;
            ph.f[0] = hh0; ph.f[1] = hh1; ph.f[2] = hh2; ph.f[3] = hh3;
            pl.f[0] = ll0; pl.f[1] = ll1; pl.f[2] = ll2; pl.f[3] = ll3;
            *(uint2*)((char*)Xh + o) = ph.u;
            *(uint2*)((char*)Xl + o) = pl.u;
        }
    }
    __syncthreads();

    f32x4 acc[4][2];
#pragma unroll
    for (int mt = 0; mt < 4; mt++)
#pragma unroll
        for (int nt = 0; nt < 2; nt++) acc[mt][nt] = (f32x4){0.f, 0.f, 0.f, 0.f};

#pragma unroll
    for (int ks = 0; ks < 8; ks++) {
        f16x4 ah[4], al[4];
#pragma unroll
        for (int mt = 0; mt < 4; mt++) {
            int h = (mt << 4) + (lane & 15);
            int oc = (ks << 5) + ((lane >> 4) << 3);
            int o = (h << 8) + (oc ^ ((h & 7) << 4));
            ah[mt] = *(const f16x4*)((char*)Xh + o);
            al[mt] = *(const f16x4*)((char*)Xl + o);
        }
#pragma unroll
        for (int mt = 0; mt < 4; mt++)
#pragma unroll
            for (int nt = 0; nt < 2; nt++) {
                acc[mt][nt] = __builtin_amdgcn_mfma_f32_16x16x16f16(ah[mt], wh[nt][ks], acc[mt][nt], 0, 0, 0);
                acc[mt][nt] = __builtin_amdgcn_mfma_f32_16x16x16f16(al[mt], wh[nt][ks], acc[mt][nt], 0, 0, 0);
                acc[mt][nt] = __builtin_amdgcn_mfma_f32_16x16x16f16(ah[mt], wl[nt][ks], acc[mt][nt], 0, 0, 0);
            }
    }

    // store D: col=lane&15 -> r, row=(lane>>4)*4+reg -> h
    float* dst = ((w < 4) ? Ab : Bb) + n * NEL;
    int rbase = (w & 3) << 5;
#pragma unroll
    for (int mt = 0; mt < 4; mt++) {
        int hb = (mt << 4) + ((lane >> 4) << 2);
#pragma unroll
        for (int nt = 0; nt < 2; nt++) {
            int r = rbase + (nt << 4) + (lane & 15);
#pragma unroll
            for (int reg = 0; reg < 4; reg++) {
                int h = hb + reg;
                if (h < HH) dst[h * 128 + r] = acc[mt][nt][reg];
            }
        }
    }
}

// ---------------- per-dst aggregation in hc layout ----------------
template<bool LAST>
__global__ __launch_bounds__(256) void k_edge(
    const float* __restrict__ A, const float* __restrict__ Bm,
    const float* __restrict__ ea, const float* __restrict__ M3, const float* __restrict__ v3,
    const float* __restrict__ gp, const float* __restrict__ bp,
    const int* __restrict__ off, const int* __restrict__ ssrc, const int* __restrict__ seid,
    float* __restrict__ out) {
    int d = blockIdx.x, t = threadIdx.x;
    __shared__ float c3all[16 * 128];
    __shared__ float red[2][8];

    int j0 = off[d], j1 = off[d + 1], cnt = j1 - j0;

    for (int idx = t; idx < (cnt << 7); idx += 256) {
        int j = idx >> 7, c = idx & 127;
        int eid = seid[j0 + j];
        const float* eap = ea + eid * 5;
        const float* m = M3 + c * 5;
        c3all[idx] = v3[c] + m[0]*eap[0] + m[1]*eap[1] + m[2]*eap[2] + m[3]*eap[3] + m[4]*eap[4];
    }

    float2 areg[15], greg[15], breg[15], accv[15], bv[15], bvn[15];
    const float2* A2 = (const float2*)(A + d * NEL);
    const float2* g2 = (const float2*)gp;
    const float2* b2 = (const float2*)bp;
#pragma unroll
    for (int i = 0; i < 15; i++) {
        int p = t + (i << 8);
        areg[i] = A2[p]; greg[i] = g2[p]; breg[i] = b2[p];
        accv[i] = make_float2(0.f, 0.f);
    }
    {   // prefetch first edge
        const float2* B2 = (const float2*)(Bm + ssrc[j0] * NEL);
#pragma unroll
        for (int i = 0; i < 15; i++) bv[i] = B2[t + (i << 8)];
    }
    __syncthreads();

    for (int j = 0; j < cnt; j++) {
        if (j + 1 < cnt) {
            const float2* B2 = (const float2*)(Bm + ssrc[j0 + j + 1] * NEL);
#pragma unroll
            for (int i = 0; i < 15; i++) bvn[i] = B2[t + (i << 8)];
        }
        float2 cc = ((const float2*)(c3all + ((j & 15) << 7)))[t & 63];
        float sum = 0.f, sq = 0.f;
#pragma unroll
        for (int i = 0; i < 15; i++) {
            float vx = areg[i].x + bv[i].x + cc.x;
            float vy = areg[i].y + bv[i].y + cc.y;
            sum += vx + vy;
            sq = fmaf(vx, vx, fmaf(vy, vy, sq));
        }
#pragma unroll
        for (int o = 32; o; o >>= 1) { sum += __shfl_xor(sum, o); sq += __shfl_xor(sq, o); }
        int jb = j & 1;
        if ((t & 63) == 0) { red[jb][(t >> 6) * 2] = sum; red[jb][(t >> 6) * 2 + 1] = sq; }
        asm volatile("s_waitcnt lgkmcnt(0)" ::: "memory");
        __builtin_amdgcn_s_barrier();
        float fs = red[jb][0] + red[jb][2] + red[jb][4] + red[jb][6];
        float fq = red[jb][1] + red[jb][3] + red[jb][5] + red[jb][7];
        float mu = fs * (1.0f / NEL);
        float var = fq * (1.0f / NEL) - mu * mu;
        float rs = rsqrtf(var + 1e-5f);
#pragma unroll
        for (int i = 0; i < 15; i++) {
            float vx = areg[i].x + bv[i].x + cc.x;
            float vy = areg[i].y + bv[i].y + cc.y;
            float nx = (vx - mu) * rs * greg[i].x + breg[i].x;
            float ny = (vy - mu) * rs * greg[i].y + breg[i].y;
            accv[i].x += fmaxf(nx, 0.f);
            accv[i].y += fmaxf(ny, 0.f);
            bv[i] = bvn[i];
        }
    }

    if (LAST) {
#pragma unroll
        for (int i = 0; i < 15; i++) {
            int q = (t + (i << 8)) << 1;
            int c = q & 127, h = q >> 7;
            out[d * NEL + c * HH + h] = accv[i].x;
            out[d * NEL + (c + 1) * HH + h] = accv[i].y;
        }
    } else {
        float2* out2 = (float2*)(out + d * NELP);
#pragma unroll
        for (int i = 0; i < 15; i++) out2[t + (i << 8)] = accv[i];
        out2[3840 + t] = make_float2(0.f, 0.f);   // zero pad rows 60..63
    }
}

extern "C" void kernel_launch(void* const* d_in, const int* in_sizes, int n_in,
                              void* d_out, int out_size, void* d_ws, size_t ws_size,
                              hipStream_t stream) {
    const float* x  = (const float*)d_in[0];
    const float* ea = (const float*)d_in[1];
    const float* ew = (const float*)d_in[2];
    const float* eb = (const float*)d_in[3];
    const float* cw = (const float*)d_in[4];
    const float* lg = (const float*)d_in[5];
    const float* lb = (const float*)d_in[6];
    const int*   ei = (const int*)d_in[7];
    int E = in_sizes[7] / 2;
    float* out = (float*)d_out;

    float* wsf  = (float*)d_ws;
    float* Abuf = wsf;                         // 384*7680
    float* Bbuf = Abuf + NN * NEL;             // 384*7680
    float* xbuf = Bbuf + NN * NEL;             // 384*8192 (hc padded)
    float* gp   = xbuf + NN * NELP;            // 4*7680
    float* bp   = gp + NLAYERS * NEL;          // 4*7680
    float* M3   = bp + NLAYERS * NEL;          // 4*640
    float* v3   = M3 + NLAYERS * CC * 5;       // 4*128
    _Float16* wfh = (_Float16*)(v3 + NLAYERS * CC);   // 4*32768 f16
    _Float16* wfl = wfh + NLAYERS * 32768;
    int* off  = (int*)(wfl + NLAYERS * 32768); // 385
    int* ssrc = off + (NN + 1);                // E
    int* seid = ssrc + E;                      // E

    k_sort<<<1, 256, 0, stream>>>(ei, E, off, ssrc, seid);
    k_prep<<<4, 128, 0, stream>>>(cw, ew, eb, M3, v3);
    k_wfrag<<<64, 64, 0, stream>>>(cw, wfh, wfl);
    k_gbprep<<<120, 256, 0, stream>>>(lg, lb, gp, bp);

    for (int l = 0; l < NLAYERS; l++) {
        const float* xin = (l == 0) ? x : xbuf;
        float* xout = (l == NLAYERS - 1) ? out : xbuf;
        if (l == 0)
            k_mm<1><<<NN, 512, 0, stream>>>(xin, wfh + l * 32768, wfl + l * 32768, Abuf, Bbuf);
        else
            k_mm<0><<<NN, 512, 0, stream>>>(xin, wfh + l * 32768, wfl + l * 32768, Abuf, Bbuf);
        if (l == NLAYERS - 1)
            k_edge<true><<<NN, 256, 0, stream>>>(Abuf, Bbuf, ea, M3 + l * CC * 5, v3 + l * CC,
                                                 gp + l * NEL, bp + l * NEL, off, ssrc, seid, xout);
        else
            k_edge<false><<<NN, 256, 0, stream>>>(Abuf, Bbuf, ea, M3 + l * CC * 5, v3 + l * CC,
                                                  gp + l * NEL, bp + l * NEL, off, ssrc, seid, xout);
    }
}

// Round 8
// 220.033 us; speedup vs baseline: 2.0072x; 1.2217x over previous
//
#include <hip/hip_runtime.h>
#include <hip/hip_bf16.h>

#define NN 384
#define CC 128
#define HH 60
#define NEL (CC*HH)     // 7680
#define NLAYERS 4

typedef _Float16 f16x4 __attribute__((ext_vector_type(4)));
typedef float f32x4 __attribute__((ext_vector_type(4)));

__device__ __forceinline__ void cvt2(float v, _Float16& hi, _Float16& lo) {
    hi = (_Float16)v; lo = (_Float16)(v - (float)hi);
}

// ============ setup: sort (b0), edge-linear fold (b1-4), W frags (b5-20), g/b permute (b21-140) ============
__global__ __launch_bounds__(256) void k_setup(
    const float* __restrict__ cw, const float* __restrict__ ew, const float* __restrict__ eb,
    const float* __restrict__ lg, const float* __restrict__ lb, const int* __restrict__ ei, int E,
    float* __restrict__ M3, float* __restrict__ v3,
    _Float16* __restrict__ wfh, _Float16* __restrict__ wfl,
    float* __restrict__ gp, float* __restrict__ bp,
    int* __restrict__ off, int* __restrict__ ssrc, int* __restrict__ seid)
{
    int bid = blockIdx.x, t = threadIdx.x;
    if (bid == 0) {
        __shared__ int cnt[NN + 1];
        __shared__ int cur[NN];
        for (int i = t; i < NN + 1; i += 256) cnt[i] = 0;
        __syncthreads();
        const int* dstp = ei + E;
        for (int e = t; e < E; e += 256) atomicAdd(&cnt[dstp[e] + 1], 1);
        __syncthreads();
        if (t == 0) { int s = 0; for (int i = 0; i <= NN; i++) { s += cnt[i]; cnt[i] = s; } }
        __syncthreads();
        for (int i = t; i < NN + 1; i += 256) off[i] = cnt[i];
        for (int i = t; i < NN; i += 256) cur[i] = cnt[i];
        __syncthreads();
        for (int e = t; e < E; e += 256) {
            int d = dstp[e];
            int p = atomicAdd(&cur[d], 1);
            ssrc[p] = ei[e];
            seid[p] = e;
        }
    } else if (bid < 5) {
        if (t < CC) {
            int l = bid - 1, c = t;
            const float* wrow = cw + (l * CC + c) * (3 * CC) + 2 * CC;
            const float* ewl = ew + l * CC * 5;
            const float* ebl = eb + l * CC;
            float m0 = 0, m1 = 0, m2 = 0, m3 = 0, m4 = 0, v = 0;
            for (int k = 0; k < CC; k++) {
                float wv = wrow[k];
                const float* e5 = ewl + k * 5;
                m0 = fmaf(wv, e5[0], m0); m1 = fmaf(wv, e5[1], m1); m2 = fmaf(wv, e5[2], m2);
                m3 = fmaf(wv, e5[3], m3); m4 = fmaf(wv, e5[4], m4);
                v  = fmaf(wv, ebl[k], v);
            }
            float* mo = M3 + (l * CC + c) * 5;
            mo[0] = m0; mo[1] = m1; mo[2] = m2; mo[3] = m3; mo[4] = m4;
            v3[l * CC + c] = v;
        }
    } else if (bid < 21) {
        int wid = ((bid - 5) << 2) + (t >> 6);   // l*16+ng
        int lane = t & 63;
        int l = wid >> 4;
        const float* cwl = cw + l * CC * 3 * CC;
        int r = ((wid & 15) << 4) + (lane & 15);
#pragma unroll
        for (int kt = 0; kt < 8; kt++) {
#pragma unroll
            for (int j = 0; j < 4; j++) {
                int k = (kt << 4) + ((lane >> 4) << 2) + j;
                float wv;
                if (r < 128) wv = cwl[r * 384 + k] - cwl[r * 384 + 128 + k];
                else         wv = cwl[(r - 128) * 384 + 128 + k];
                _Float16 hi, lo; cvt2(wv, hi, lo);
                int idx = (wid * 8 + kt) * 256 + lane * 4 + j;
                wfh[idx] = hi; wfl[idx] = lo;
            }
        }
    } else if (bid < 141) {
        int gidx = ((bid - 21) << 8) + t;       // 0..30719
        int l = gidx / NEL, q = gidx - l * NEL;
        int c = q & 127, h = q >> 7;            // gp layout [l][h*128+c]
        gp[gidx] = lg[l * NEL + c * HH + h];
        bp[gidx] = lb[l * NEL + c * HH + h];
    }
}

// ============ MFMA core: D[(n*60+h)*256 + r] = sum_k X[h][k] * Wcomb[r][k], f16 x3 split ============
__device__ __forceinline__ void mm_core(char* XhB, char* XlB,
                                        const _Float16* __restrict__ wfhL,
                                        const _Float16* __restrict__ wflL,
                                        float* __restrict__ Dout, int n, int w, int lane)
{
    f16x4 whv[4][8], wlv[4][8];
#pragma unroll
    for (int nt = 0; nt < 4; nt++)
#pragma unroll
        for (int kt = 0; kt < 8; kt++) {
            int idx = (((((w << 2) + nt) << 3) + kt) << 8) + (lane << 2);
            whv[nt][kt] = *(const f16x4*)(wfhL + idx);
            wlv[nt][kt] = *(const f16x4*)(wflL + idx);
        }
    f32x4 acc[4][4];
#pragma unroll
    for (int mt = 0; mt < 4; mt++)
#pragma unroll
        for (int nt = 0; nt < 4; nt++) acc[mt][nt] = (f32x4){0.f, 0.f, 0.f, 0.f};

#pragma unroll
    for (int ks = 0; ks < 8; ks++) {
        f16x4 ah[4], al[4];
#pragma unroll
        for (int mt = 0; mt < 4; mt++) {
            int h = (mt << 4) + (lane & 15);
            int o = (h << 8) + (((ks << 5) + ((lane >> 4) << 3)) ^ ((h & 7) << 4));
            ah[mt] = *(const f16x4*)(XhB + o);
            al[mt] = *(const f16x4*)(XlB + o);
        }
#pragma unroll
        for (int mt = 0; mt < 4; mt++)
#pragma unroll
            for (int nt = 0; nt < 4; nt++) {
                acc[mt][nt] = __builtin_amdgcn_mfma_f32_16x16x16f16(ah[mt], whv[nt][ks], acc[mt][nt], 0, 0, 0);
                acc[mt][nt] = __builtin_amdgcn_mfma_f32_16x16x16f16(al[mt], whv[nt][ks], acc[mt][nt], 0, 0, 0);
                acc[mt][nt] = __builtin_amdgcn_mfma_f32_16x16x16f16(ah[mt], wlv[nt][ks], acc[mt][nt], 0, 0, 0);
            }
    }
    int rb = w << 6;
#pragma unroll
    for (int mt = 0; mt < 4; mt++) {
        int hb = (mt << 4) + ((lane >> 4) << 2);
#pragma unroll
        for (int nt = 0; nt < 4; nt++) {
            int r = rb + (nt << 4) + (lane & 15);
#pragma unroll
            for (int reg = 0; reg < 4; reg++) {
                int h = hb + reg;
                if (h < HH) Dout[(n * HH + h) * 256 + r] = acc[mt][nt][reg];
            }
        }
    }
}

// ============ layer-0 matmul from canonical x ============
__global__ __launch_bounds__(256, 2) void k_mm0(const float* __restrict__ x,
                                                const _Float16* __restrict__ wfhL,
                                                const _Float16* __restrict__ wflL,
                                                float* __restrict__ Dout)
{
    __shared__ __align__(16) char smem[33024];
    char* XhB = smem;
    char* XlB = smem + 16384;
    int n = blockIdx.x, t = threadIdx.x;
    int w = t >> 6, lane = t & 63;

    const float* xn = x + n * NEL;
    for (int p = t; p < 3840; p += 256) {
        int q = p << 1;
        int c = q & 127, h = q >> 7;
        float v0 = xn[c * HH + h], v1 = xn[(c + 1) * HH + h];
        _Float16 h0, l0, h1, l1; cvt2(v0, h0, l0); cvt2(v1, h1, l1);
        int o = (h << 8) + ((c << 1) ^ ((h & 7) << 4));
        union { _Float16 f[2]; unsigned u; } ph, pl;
        ph.f[0] = h0; ph.f[1] = h1; pl.f[0] = l0; pl.f[1] = l1;
        *(unsigned*)(XhB + o) = ph.u;
        *(unsigned*)(XlB + o) = pl.u;
    }
    if (t < 64) {   // zero pad rows 60..63
        int h = 60 + (t >> 4), ch = t & 15;
        int o = (h << 8) + ((ch << 4) ^ ((h & 7) << 4));
        *(uint4*)(XhB + o) = make_uint4(0, 0, 0, 0);
        *(uint4*)(XlB + o) = make_uint4(0, 0, 0, 0);
    }
    __syncthreads();
    mm_core(XhB, XlB, wfhL, wflL, Dout, n, w, lane);
}

// ============ fused: EDGE(layer l over Din) [+ MM(layer l+1) -> Dout | final store] ============
template<bool LAST>
__global__ __launch_bounds__(256, 2) void k_fused(
    const float* __restrict__ Din, const float* __restrict__ ea,
    const float* __restrict__ M3l, const float* __restrict__ v3l,
    const float* __restrict__ gpl, const float* __restrict__ bpl,
    const int* __restrict__ off, const int* __restrict__ ssrc, const int* __restrict__ seid,
    const _Float16* __restrict__ wfhL, const _Float16* __restrict__ wflL,
    float* __restrict__ Dout)
{
    __shared__ __align__(16) char smem[33024];
    int d = blockIdx.x, t = threadIdx.x;
    int w = t >> 6, lane = t & 63;
    float* c3all = (float*)smem;          // 16*128 f32 (aliases Xh planes, reused later)
    float* red   = c3all + 2048;          // 16 f32

    int j0 = off[d], j1 = off[d + 1], cnt = j1 - j0;

    for (int idx = t; idx < (cnt << 7); idx += 256) {
        int j = idx >> 7, c = idx & 127;
        int eid = seid[j0 + j];
        const float* eap = ea + eid * 5;
        const float* m = M3l + c * 5;
        c3all[idx] = v3l[c] + m[0]*eap[0] + m[1]*eap[1] + m[2]*eap[2] + m[3]*eap[3] + m[4]*eap[4];
    }

    float2 areg[15], greg[15], breg[15], accv[15], bv[15], bvn[15];
    const float2* D2 = (const float2*)Din;
    const float2* g2 = (const float2*)gpl;
    const float2* b2 = (const float2*)bpl;
#pragma unroll
    for (int i = 0; i < 15; i++) {
        int p = t + (i << 8);
        areg[i] = D2[(d * HH + (p >> 6)) * 128 + (p & 63)];
        greg[i] = g2[p]; breg[i] = b2[p];
        accv[i] = make_float2(0.f, 0.f);
    }
    {
        int s = ssrc[j0];
#pragma unroll
        for (int i = 0; i < 15; i++) {
            int p = t + (i << 8);
            bv[i] = D2[(s * HH + (p >> 6)) * 128 + 64 + (p & 63)];
        }
    }
    __syncthreads();

    for (int j = 0; j < cnt; j++) {
        if (j + 1 < cnt) {
            int s = ssrc[j0 + j + 1];
#pragma unroll
            for (int i = 0; i < 15; i++) {
                int p = t + (i << 8);
                bvn[i] = D2[(s * HH + (p >> 6)) * 128 + 64 + (p & 63)];
            }
        }
        float2 cc = ((const float2*)c3all)[(j << 6) + (t & 63)];
        float sum = 0.f, sq = 0.f;
#pragma unroll
        for (int i = 0; i < 15; i++) {
            float vx = areg[i].x + bv[i].x + cc.x;
            float vy = areg[i].y + bv[i].y + cc.y;
            sum += vx + vy;
            sq = fmaf(vx, vx, fmaf(vy, vy, sq));
        }
#pragma unroll
        for (int o = 32; o; o >>= 1) { sum += __shfl_xor(sum, o); sq += __shfl_xor(sq, o); }
        int jb = j & 1;
        if ((t & 63) == 0) { red[jb * 8 + (t >> 6) * 2] = sum; red[jb * 8 + (t >> 6) * 2 + 1] = sq; }
        asm volatile("s_waitcnt lgkmcnt(0)" ::: "memory");
        __builtin_amdgcn_s_barrier();
        float fs = red[jb*8+0] + red[jb*8+2] + red[jb*8+4] + red[jb*8+6];
        float fq = red[jb*8+1] + red[jb*8+3] + red[jb*8+5] + red[jb*8+7];
        float mu = fs * (1.0f / NEL);
        float var = fq * (1.0f / NEL) - mu * mu;
        float rs = rsqrtf(var + 1e-5f);
#pragma unroll
        for (int i = 0; i < 15; i++) {
            float vx = areg[i].x + bv[i].x + cc.x;
            float vy = areg[i].y + bv[i].y + cc.y;
            float nx = (vx - mu) * rs * greg[i].x + breg[i].x;
            float ny = (vy - mu) * rs * greg[i].y + breg[i].y;
            accv[i].x += fmaxf(nx, 0.f);
            accv[i].y += fmaxf(ny, 0.f);
            bv[i] = bvn[i];
        }
    }

    if (LAST) {
#pragma unroll
        for (int i = 0; i < 15; i++) {
            int p = t + (i << 8);
            int h = p >> 6, c = (p & 63) << 1;
            Dout[d * NEL + c * HH + h] = accv[i].x;
            Dout[d * NEL + (c + 1) * HH + h] = accv[i].y;
        }
    } else {
        // restage accv (= x_{l+1}[d]) into f16 hi/lo LDS planes, then MFMA for layer l+1
        __syncthreads();    // c3all reads done; smem reused for X planes
        char* XhB = smem;
        char* XlB = smem + 16384;
#pragma unroll
        for (int i = 0; i < 15; i++) {
            int p = t + (i << 8);
            int h = p >> 6;
            int cb = (p & 63) << 2;    // byte col of element 2*(p&63)
            int o = (h << 8) + (cb ^ ((h & 7) << 4));
            _Float16 h0, l0, h1, l1;
            cvt2(accv[i].x, h0, l0); cvt2(accv[i].y, h1, l1);
            union { _Float16 f[2]; unsigned u; } ph, pl;
            ph.f[0] = h0; ph.f[1] = h1; pl.f[0] = l0; pl.f[1] = l1;
            *(unsigned*)(XhB + o) = ph.u;
            *(unsigned*)(XlB + o) = pl.u;
        }
        if (t < 64) {
            int h = 60 + (t >> 4), ch = t & 15;
            int o = (h << 8) + ((ch << 4) ^ ((h & 7) << 4));
            *(uint4*)(XhB + o) = make_uint4(0, 0, 0, 0);
            *(uint4*)(XlB + o) = make_uint4(0, 0, 0, 0);
        }
        __syncthreads();
        mm_core(XhB, XlB, wfhL, wflL, Dout, d, w, lane);
    }
}

extern "C" void kernel_launch(void* const* d_in, const int* in_sizes, int n_in,
                              void* d_out, int out_size, void* d_ws, size_t ws_size,
                              hipStream_t stream) {
    const float* x  = (const float*)d_in[0];
    const float* ea = (const float*)d_in[1];
    const float* ew = (const float*)d_in[2];
    const float* eb = (const float*)d_in[3];
    const float* cw = (const float*)d_in[4];
    const float* lg = (const float*)d_in[5];
    const float* lb = (const float*)d_in[6];
    const int*   ei = (const int*)d_in[7];
    int E = in_sizes[7] / 2;
    float* out = (float*)d_out;

    float* wsf = (float*)d_ws;
    float* D0 = wsf;                                   // 384*60*256
    float* D1 = D0 + NN * HH * 256;                    // 384*60*256
    float* gp = D1 + NN * HH * 256;                    // 4*7680
    float* bp = gp + NLAYERS * NEL;                    // 4*7680
    float* M3 = bp + NLAYERS * NEL;                    // 4*640
    float* v3 = M3 + NLAYERS * 640;                    // 4*128
    _Float16* wfh = (_Float16*)(v3 + NLAYERS * 128);   // 4*32768
    _Float16* wfl = wfh + NLAYERS * 32768;             // 4*32768
    int* off  = (int*)(wfl + NLAYERS * 32768);         // 385
    int* ssrc = off + (NN + 1);                        // E
    int* seid = ssrc + E;                              // E

    k_setup<<<141, 256, 0, stream>>>(cw, ew, eb, lg, lb, ei, E,
                                     M3, v3, wfh, wfl, gp, bp, off, ssrc, seid);
    k_mm0<<<NN, 256, 0, stream>>>(x, wfh, wfl, D0);

    // layer l: EDGE over D(cur) [+ MM layer l+1 -> D(next)]
    k_fused<false><<<NN, 256, 0, stream>>>(D0, ea, M3 + 0 * 640, v3 + 0 * 128,
                                           gp + 0 * NEL, bp + 0 * NEL, off, ssrc, seid,
                                           wfh + 1 * 32768, wfl + 1 * 32768, D1);
    k_fused<false><<<NN, 256, 0, stream>>>(D1, ea, M3 + 1 * 640, v3 + 1 * 128,
                                           gp + 1 * NEL, bp + 1 * NEL, off, ssrc, seid,
                                           wfh + 2 * 32768, wfl + 2 * 32768, D0);
    k_fused<false><<<NN, 256, 0, stream>>>(D0, ea, M3 + 2 * 640, v3 + 2 * 128,
                                           gp + 2 * NEL, bp + 2 * NEL, off, ssrc, seid,
                                           wfh + 3 * 32768, wfl + 3 * 32768, D1);
    k_fused<true><<<NN, 256, 0, stream>>>(D1, ea, M3 + 3 * 640, v3 + 3 * 128,
                                          gp + 3 * NEL, bp + 3 * NEL, off, ssrc, seid,
                                          wfh, wfl, out);
}